// Round 11
// baseline (76.488 us; speedup 1.0000x reference)
//
#include <hip/hip_runtime.h>

// S4D kernel materialization:
//   dt = exp(log_dt[h]) ; A = -exp(log_A_real) + i*A_imag
//   dtA = A*dt ; w = exp(dtA) ; Cc = C*(w-1)/A
//   K[h,l] = 2 * Re( sum_n Cc[h,n] * w[h,n]^l )
//
// R10 diagnosis: packed-FP32 halved VALU; LDS pipe (32 b128 reads/thread)
// is now the roof (~5.1us of ~10.3us kernel). R11: eliminate the loB table;
// reconstruct the second Chebyshev seed in registers:
//   s0 = lo*hi; x0 = Re(s0); y0 = Im(s0); x1 = Wre*x0 - Wim*y0
//   aW = 2*Wre; bW = -(Wre^2+Wim^2)   (from s_abW = (Wre0,Wre1,Wim0,Wim1))
// -> 3 b128 reads per pair (was 4), +5 packed ops on the idle VALU pipe.
// BLK=512, 2-way mode-split, J=16, packed 2-modes-per-register throughout.

typedef float v2f __attribute__((ext_vector_type(2)));

static __device__ __forceinline__ float2 cmul(float2 a, float2 b) {
    return make_float2(fmaf(a.x, b.x, -(a.y * b.y)),
                       fmaf(a.x, b.y,   a.y * b.x));
}

template <int N2, int CPB, int J>
__global__ __launch_bounds__(2 * CPB, 8) void s4d_kernel(
    const float* __restrict__ C,
    const float* __restrict__ log_dt,
    const float* __restrict__ log_A_real,
    const float* __restrict__ A_imag,
    float* __restrict__ K,
    int L)
{
    constexpr int NP  = N2 / 2;          // mode pairs (16)
    constexpr int PPG = NP / 2;          // pairs per wave-group (8)
    __shared__ float4 s_loA[NP][16];     // (re0,re1,im0,im1): lo = 2Cc*w^(lbase+k)
    __shared__ float4 s_hiq[NP][16];     // (re0,re1,im0,im1): (w^16)^k
    __shared__ float4 s_abW[NP];         // (Wre0,Wre1,Wim0,Wim1), W = w^CPB
    __shared__ float  s_part[J][CPB];    // group-1 partial sums (16 KB)

    const int h = blockIdx.x;
    const int y = blockIdx.y;
    const int lbase = y * (CPB * J);
    const int t = threadIdx.x;

    // ---- Parallel setup: thread t (0..511) builds entry (n = t>>4, k = t&15) ----
    {
        const int n   = t >> 4;          // 0..31
        const int k   = t & 15;
        const int p   = n >> 1;          // pair index
        const int c01 = n & 1;           // slot within pair

        const float dt  = expf(log_dt[h]);
        const float Are = -expf(log_A_real[h * N2 + n]);
        const float Aim = A_imag[h * N2 + n];
        const float dre = Are * dt;
        const float dim = Aim * dt;      // |dim| <= ~9.7 rad: fast sincos path
        float sw, cw;
        sincosf(dim, &sw, &cw);
        const float er = expf(dre);
        const float2 w = make_float2(er * cw, er * sw);
        // 2*Cc = 2*C*(w-1)/A
        const float nre = w.x - 1.0f;
        const float nim = w.y;
        const float inv = 1.0f / (Are * Are + Aim * Aim);
        const float cc  = 2.0f * C[h * N2 + n];
        const float2 c  = make_float2(cc * ((nre * Are + nim * Aim) * inv),
                                      cc * ((nim * Are - nre * Aim) * inv));
        // powers of w by squaring
        const float2 w2   = cmul(w,    w);
        const float2 w4   = cmul(w2,   w2);
        const float2 w8   = cmul(w4,   w4);
        const float2 w16  = cmul(w8,   w8);
        const float2 w32  = cmul(w16,  w16);
        const float2 w64  = cmul(w32,  w32);
        const float2 w128 = cmul(w64,  w64);
        const float2 W    = cmul(w128, w128);   // w^256 == w^CPB

        const float2 ONE = make_float2(1.0f, 0.0f);
        // w^k, k<16: product of selected {w,w2,w4,w8}
        float2 pk = (k & 1) ? w : ONE;
        pk = cmul(pk, (k & 2) ? w2 : ONE);
        pk = cmul(pk, (k & 4) ? w4 : ONE);
        pk = cmul(pk, (k & 8) ? w8 : ONE);
        // (w^16)^k: product of selected {w16,w32,w64,w128}
        float2 qk = (k & 1) ? w16 : ONE;
        qk = cmul(qk, (k & 2) ? w32  : ONE);
        qk = cmul(qk, (k & 4) ? w64  : ONE);
        qk = cmul(qk, (k & 8) ? w128 : ONE);

        // w^lbase = W^(J*y), block-uniform binary pow (no-op when y==0)
        float2 P = ONE;
        {
            float2 base = W;
            int ee = J * y;
            while (ee) { if (ee & 1) P = cmul(P, base); base = cmul(base, base); ee >>= 1; }
        }

        const float2 lo = cmul(cmul(c, P), pk);   // 2Cc * w^(lbase+k)

        // Pair-interleaved scalar writes (even/odd n hit disjoint components)
        float* pA = (float*)&s_loA[p][k];
        float* pH = (float*)&s_hiq[p][k];
        pA[c01] = lo.x; pA[2 + c01] = lo.y;
        pH[c01] = qk.x; pH[2 + c01] = qk.y;
        if (k == 0) {
            float* pW = (float*)&s_abW[p];
            pW[c01] = W.x; pW[2 + c01] = W.y;
        }
    }
    __syncthreads();

    v2f acc[J];
#pragma unroll
    for (int j = 0; j < J; ++j) acc[j] = (v2f){0.0f, 0.0f};

    const int col = t & (CPB - 1);       // sample column 0..255
    const int g   = t / CPB;             // wave-group 0/1
    const int tlo = col & 15;
    const int thi = col >> 4;
    const int pb  = g * PPG;

#pragma unroll 2
    for (int pp = 0; pp < PPG; ++pp) {
        const float4 la = s_loA[pb + pp][tlo];
        const float4 hq = s_hiq[pb + pp][thi];
        const float4 wq = s_abW[pb + pp];

        const v2f lre = {la.x, la.y}, lim = {la.z, la.w};
        const v2f hre = {hq.x, hq.y}, him = {hq.z, hq.w};
        const v2f wre = {wq.x, wq.y}, wim = {wq.z, wq.w};

        const v2f aw = wre + wre;                 // 2*Re(W)
        const v2f bw = -(wre * wre + wim * wim);  // -|W|^2

        v2f x0 = lre * hre - lim * him;           // Re(s0), s0 = lo*hi
        const v2f y0 = lre * him + lim * hre;     // Im(s0)
        v2f x1 = wre * x0 - wim * y0;             // Re(s0 * W)
        acc[0] += x0;
        acc[1] += x1;
#pragma unroll
        for (int j = 2; j < J; ++j) {
            const v2f x2 = aw * x1 + bw * x0;     // 2Re(W)x1 - |W|^2 x0
            acc[j] += x2;
            x0 = x1;
            x1 = x2;
        }
    }

    // ---- Cross-group reduction + store ----
    if (g == 1) {
#pragma unroll
        for (int j = 0; j < J; ++j) s_part[j][col] = acc[j].x + acc[j].y;
    }
    __syncthreads();
    if (g == 0) {
        float* __restrict__ outp = K + (size_t)h * (size_t)L + lbase + col;
#pragma unroll
        for (int j = 0; j < J; ++j) {
            const float r = acc[j].x + acc[j].y + s_part[j][col];
            const int l = lbase + j * CPB + col;
            if (l < L) outp[(size_t)j * CPB] = r;
        }
    }
}

extern "C" void kernel_launch(void* const* d_in, const int* in_sizes, int n_in,
                              void* d_out, int out_size, void* d_ws, size_t ws_size,
                              hipStream_t stream)
{
    const float* C          = (const float*)d_in[0];
    const float* log_dt     = (const float*)d_in[1];
    const float* log_A_real = (const float*)d_in[2];
    const float* A_imag     = (const float*)d_in[3];
    float* K = (float*)d_out;

    const int H   = in_sizes[1];           // 1024
    const int N2v = in_sizes[0] / H;       // 32
    const int L   = out_size / H;          // 4096
    constexpr int CPB = 256;               // sample columns per block
    constexpr int J   = 16;                // samples per column per block
    const int gy = (L + CPB * J - 1) / (CPB * J);   // 1 for L=4096

    if (N2v != 32) return;
    dim3 grid((unsigned)H, (unsigned)gy);
    s4d_kernel<32, CPB, J><<<grid, 2 * CPB, 0, stream>>>(
        C, log_dt, log_A_real, A_imag, K, L);
}